// Round 1
// baseline (386.757 us; speedup 1.0000x reference)
//
#include <hip/hip_runtime.h>

#define NS 7
#define NA 131072
#define AEVD 1008
#define KP1 1024
#define N1 256
#define N2 192
#define N3 160

typedef __attribute__((ext_vector_type(8))) short short8;
typedef __attribute__((ext_vector_type(8))) unsigned short ushortx8;
typedef __attribute__((ext_vector_type(4))) float f32x4;
typedef unsigned short u16;

__device__ __forceinline__ u16 f2bf(float f) {
  unsigned u = __builtin_bit_cast(unsigned, f);
  u += 0x7fffu + ((u >> 16) & 1u);
  return (u16)(u >> 16);
}
__device__ __forceinline__ float bf2f(u16 h) {
  return __builtin_bit_cast(float, ((unsigned)h) << 16);
}
__device__ __forceinline__ float celu_f(float x) {
  return x > 0.f ? x : 0.1f * (__expf(x * 10.f) - 1.f);
}

// ---------------- bucketing ----------------
__global__ void count_kernel(const int* __restrict__ species, int* __restrict__ counts) {
  __shared__ int h[NS];
  if (threadIdx.x < NS) h[threadIdx.x] = 0;
  __syncthreads();
  int i = blockIdx.x * blockDim.x + threadIdx.x;
  if (i < NA) atomicAdd(&h[species[i]], 1);
  __syncthreads();
  if (threadIdx.x < NS) atomicAdd(&counts[threadIdx.x], h[threadIdx.x]);
}

__global__ void scan_kernel(const int* __restrict__ counts, int* __restrict__ offsets,
                            int* __restrict__ cursors, int* __restrict__ blockStart) {
  int off = 0, bs = 0;
  for (int e = 0; e < NS; ++e) {
    offsets[e] = off; cursors[e] = off; blockStart[e] = bs;
    off += counts[e];
    bs += (counts[e] + 63) >> 6;
  }
  offsets[NS] = off; blockStart[NS] = bs;
}

__global__ void scatter_kernel(const int* __restrict__ species, int* __restrict__ cursors,
                               int* __restrict__ idx) {
  __shared__ int h[NS], lb[NS];
  if (threadIdx.x < NS) h[threadIdx.x] = 0;
  __syncthreads();
  int i = blockIdx.x * blockDim.x + threadIdx.x;
  int s = species[i];
  int lpos = atomicAdd(&h[s], 1);
  __syncthreads();
  if (threadIdx.x < NS) lb[threadIdx.x] = atomicAdd(&cursors[threadIdx.x], h[threadIdx.x]);
  __syncthreads();
  idx[lb[s] + lpos] = i;
}

// ---------------- weight convert: dst[e][n][kp] = bf16(src[e][k][n]), zero pad k>=K ----------------
__global__ void convert_w(const float* __restrict__ src, u16* __restrict__ dst,
                          int K, int N, int KP) {
  long total = (long)NS * N * KP;
  for (long i = (long)blockIdx.x * blockDim.x + threadIdx.x; i < total;
       i += (long)gridDim.x * blockDim.x) {
    int kp = (int)(i % KP);
    long t2 = i / KP;
    int n = (int)(t2 % N);
    int e = (int)(t2 / N);
    float v = (kp < K) ? src[((long)e * K + kp) * N + n] : 0.f;
    dst[i] = f2bf(v);
  }
}

// ---------------- fused MLP ----------------
// LDS pitches (in u16 elements)
#define AP 40    // A-stage pitch (32 + 8 pad) -> 80B rows, 16B aligned, 2-way banks
#define WP 40    // W-stage pitch
#define H1P 264  // h1 pitch (256 + 8)
#define H2P 200  // h2 pitch (192 + 8)
#define H3P 168  // h3 pitch (160 + 8)

__global__ __launch_bounds__(256, 2) void ani_fused(
    const int* __restrict__ idx, const int* __restrict__ counts,
    const int* __restrict__ offsets, const int* __restrict__ blockStart,
    const float* __restrict__ aev,
    const u16* __restrict__ W1t, const float* __restrict__ b1,
    const u16* __restrict__ W2t, const float* __restrict__ b2,
    const u16* __restrict__ W3t, const float* __restrict__ b3,
    const u16* __restrict__ Wht, const float* __restrict__ bh,
    float* __restrict__ out) {
  // R1: layer1 A-stage (64x40) + W-stage (256x40) = 12800 u16; reused as W2/W3 stage and h3
  // R2: h1 (64x264) = 16896 u16; reused as h2 (64x200)
  __shared__ __align__(16) u16 R1[12800];
  __shared__ __align__(16) u16 R2[16896];

  int bid = blockIdx.x;
  int total = blockStart[NS];
  if (bid >= total) return;
  int e = 0;
#pragma unroll
  for (int s = 1; s < NS; ++s)
    if (bid >= blockStart[s]) e = s;
  int t = bid - blockStart[e];
  int base = offsets[e] + (t << 6);
  int mcount = counts[e] - (t << 6);
  if (mcount > 64) mcount = 64;

  int tid = threadIdx.x;
  int lane = tid & 63;
  int w = tid >> 6;       // wave 0..3
  int lr = lane & 15;     // row/col selector within fragment
  int kg = lane >> 4;     // k-group 0..3

  // per-thread A staging assignment: row = tid>>2, k-sub = (tid&3)*8
  int arow = tid >> 2;
  int akq = (tid & 3) << 3;
  const float* aevRow = nullptr;
  if (arow < mcount) aevRow = aev + (size_t)idx[base + arow] * AEVD;

  // ---------- layer 1: [64 x 1008] @ [1008 x 256] ----------
  f32x4 acc[4][4] = {};
  const u16* W1base = W1t + (size_t)e * N1 * KP1;
  for (int k0 = 0; k0 < KP1; k0 += 32) {
    // stage A chunk (fp32 -> bf16)
    {
      float v[8] = {0.f, 0.f, 0.f, 0.f, 0.f, 0.f, 0.f, 0.f};
      if (aevRow != nullptr && (k0 + akq) < AEVD) {
        const float4* p = (const float4*)(aevRow + k0 + akq);
        float4 x = p[0], y = p[1];
        v[0] = x.x; v[1] = x.y; v[2] = x.z; v[3] = x.w;
        v[4] = y.x; v[5] = y.y; v[6] = y.z; v[7] = y.w;
      }
      ushortx8 pk;
#pragma unroll
      for (int j = 0; j < 8; ++j) pk[j] = f2bf(v[j]);
      *(ushortx8*)&R1[arow * AP + akq] = pk;
    }
    // stage W1 chunk: rows n = tid, 32 bf16 each
    {
      const ushortx8* s = (const ushortx8*)(W1base + (size_t)tid * KP1 + k0);
      ushortx8* d = (ushortx8*)&R1[2560 + tid * WP];
      d[0] = s[0]; d[1] = s[1]; d[2] = s[2]; d[3] = s[3];
    }
    __syncthreads();
    short8 af[4];
#pragma unroll
    for (int mi = 0; mi < 4; ++mi)
      af[mi] = *(const short8*)&R1[(mi * 16 + lr) * AP + kg * 8];
#pragma unroll
    for (int ni = 0; ni < 4; ++ni) {
      short8 bf = *(const short8*)&R1[2560 + (w * 64 + ni * 16 + lr) * WP + kg * 8];
#pragma unroll
      for (int mi = 0; mi < 4; ++mi)
        acc[mi][ni] = __builtin_amdgcn_mfma_f32_16x16x32_bf16(af[mi], bf, acc[mi][ni], 0, 0, 0);
    }
    __syncthreads();
  }
  // epilogue 1 -> h1 in R2 (bias + celu + bf16)
#pragma unroll
  for (int ni = 0; ni < 4; ++ni) {
    int col = w * 64 + ni * 16 + lr;
    float bias = b1[e * N1 + col];
#pragma unroll
    for (int mi = 0; mi < 4; ++mi)
#pragma unroll
      for (int r = 0; r < 4; ++r) {
        int row = mi * 16 + kg * 4 + r;
        R2[row * H1P + col] = f2bf(celu_f(acc[mi][ni][r] + bias));
      }
  }
  __syncthreads();

  // ---------- layer 2: [64 x 256] @ [256 x 192] ----------
  // wave tile: rows (w&1)*32 (2 frags), cols (w>>1)*96 (6 frags)
  int mr2 = (w & 1) * 32;
  int nc2 = (w >> 1) * 96;
  f32x4 acc2[2][6] = {};
  const u16* W2base = W2t + (size_t)e * N2 * N1;
  for (int k0 = 0; k0 < N1; k0 += 32) {
    if (tid < N2) {
      const ushortx8* s = (const ushortx8*)(W2base + (size_t)tid * N1 + k0);
      ushortx8* d = (ushortx8*)&R1[tid * WP];
      d[0] = s[0]; d[1] = s[1]; d[2] = s[2]; d[3] = s[3];
    }
    __syncthreads();
    short8 af[2];
#pragma unroll
    for (int mi = 0; mi < 2; ++mi)
      af[mi] = *(const short8*)&R2[(mr2 + mi * 16 + lr) * H1P + k0 + kg * 8];
#pragma unroll
    for (int ni = 0; ni < 6; ++ni) {
      short8 bf = *(const short8*)&R1[(nc2 + ni * 16 + lr) * WP + kg * 8];
#pragma unroll
      for (int mi = 0; mi < 2; ++mi)
        acc2[mi][ni] = __builtin_amdgcn_mfma_f32_16x16x32_bf16(af[mi], bf, acc2[mi][ni], 0, 0, 0);
    }
    __syncthreads();
  }
  // epilogue 2 -> h2 in R2 (overwrites h1 region; all reads of h1 done after last sync)
#pragma unroll
  for (int ni = 0; ni < 6; ++ni) {
    int col = nc2 + ni * 16 + lr;
    float bias = b2[e * N2 + col];
#pragma unroll
    for (int mi = 0; mi < 2; ++mi)
#pragma unroll
      for (int r = 0; r < 4; ++r) {
        int row = mr2 + mi * 16 + kg * 4 + r;
        R2[row * H2P + col] = f2bf(celu_f(acc2[mi][ni][r] + bias));
      }
  }
  __syncthreads();

  // ---------- layer 3: [64 x 192] @ [192 x 160] ----------
  int mr3 = (w & 1) * 32;
  int nc3 = (w >> 1) * 80;
  f32x4 acc3[2][5] = {};
  const u16* W3base = W3t + (size_t)e * N3 * N2;
  for (int k0 = 0; k0 < N2; k0 += 32) {
    if (tid < N3) {
      const ushortx8* s = (const ushortx8*)(W3base + (size_t)tid * N2 + k0);
      ushortx8* d = (ushortx8*)&R1[tid * WP];
      d[0] = s[0]; d[1] = s[1]; d[2] = s[2]; d[3] = s[3];
    }
    __syncthreads();
    short8 af[2];
#pragma unroll
    for (int mi = 0; mi < 2; ++mi)
      af[mi] = *(const short8*)&R2[(mr3 + mi * 16 + lr) * H2P + k0 + kg * 8];
#pragma unroll
    for (int ni = 0; ni < 5; ++ni) {
      short8 bf = *(const short8*)&R1[(nc3 + ni * 16 + lr) * WP + kg * 8];
#pragma unroll
      for (int mi = 0; mi < 2; ++mi)
        acc3[mi][ni] = __builtin_amdgcn_mfma_f32_16x16x32_bf16(af[mi], bf, acc3[mi][ni], 0, 0, 0);
    }
    __syncthreads();
  }
  __syncthreads();
  // epilogue 3 -> h3 in R1 (W3 stage dead)
#pragma unroll
  for (int ni = 0; ni < 5; ++ni) {
    int col = nc3 + ni * 16 + lr;
    float bias = b3[e * N3 + col];
#pragma unroll
    for (int mi = 0; mi < 2; ++mi)
#pragma unroll
      for (int r = 0; r < 4; ++r) {
        int row = mr3 + mi * 16 + kg * 4 + r;
        R1[row * H3P + col] = f2bf(celu_f(acc3[mi][ni][r] + bias));
      }
  }
  __syncthreads();

  // ---------- head: [64 x 160] @ [160 x 2] in fp32 VALU ----------
  if (tid < 128) {
    int r = tid >> 1, o = tid & 1;
    if (r < mcount) {
      float s = bh[e * 2 + o];
      const u16* wrow = Wht + (e * 2 + o) * N3;
      const u16* hrow = &R1[r * H3P];
#pragma unroll 8
      for (int k = 0; k < N3; ++k) s += bf2f(hrow[k]) * bf2f(wrow[k]);
      out[(size_t)idx[base + r] * 2 + o] = s;
    }
  }
}

extern "C" void kernel_launch(void* const* d_in, const int* in_sizes, int n_in,
                              void* d_out, int out_size, void* d_ws, size_t ws_size,
                              hipStream_t stream) {
  const int* species = (const int*)d_in[0];
  const float* aev = (const float*)d_in[1];
  const float* W1 = (const float*)d_in[2];
  const float* b1 = (const float*)d_in[3];
  const float* W2 = (const float*)d_in[4];
  const float* b2 = (const float*)d_in[5];
  const float* W3 = (const float*)d_in[6];
  const float* b3 = (const float*)d_in[7];
  const float* Wh = (const float*)d_in[8];
  const float* bh = (const float*)d_in[9];
  float* out = (float*)d_out;

  char* p = (char*)d_ws;
  int* counts = (int*)p; p += 32;
  int* offsets = (int*)p; p += 32;
  int* cursors = (int*)p; p += 32;
  int* blockStart = (int*)p; p += 32;
  int* idx = (int*)p; p += (size_t)NA * 4;
  u16* W1t = (u16*)p; p += (size_t)NS * N1 * KP1 * 2;
  u16* W2t = (u16*)p; p += (size_t)NS * N2 * N1 * 2;
  u16* W3t = (u16*)p; p += (size_t)NS * N3 * N2 * 2;
  u16* Wht = (u16*)p; p += (size_t)NS * 2 * N3 * 2;

  hipMemsetAsync(counts, 0, 32, stream);
  count_kernel<<<NA / 256, 256, 0, stream>>>(species, counts);
  scan_kernel<<<1, 1, 0, stream>>>(counts, offsets, cursors, blockStart);
  scatter_kernel<<<NA / 256, 256, 0, stream>>>(species, cursors, idx);

  convert_w<<<2048, 256, 0, stream>>>(W1, W1t, AEVD, N1, KP1);
  convert_w<<<1024, 256, 0, stream>>>(W2, W2t, N1, N2, N1);
  convert_w<<<512, 256, 0, stream>>>(W3, W3t, N2, N3, N2);
  convert_w<<<16, 256, 0, stream>>>(Wh, Wht, N3, 2, N3);

  int maxBlocks = (NA >> 6) + NS;  // >= sum ceil(counts/64)
  ani_fused<<<maxBlocks, 256, 0, stream>>>(idx, counts, offsets, blockStart, aev,
                                           W1t, b1, W2t, b2, W3t, b3, Wht, bh, out);
}